// Round 6
// baseline (913.691 us; speedup 1.0000x reference)
//
#include <hip/hip_runtime.h>
#include <hip/hip_bf16.h>
#include <math.h>

#define G_GRAPHS 8

// ---------- helpers ----------
__device__ __forceinline__ unsigned fmap(float f) {
    unsigned b = __float_as_uint(f);
    return (b & 0x80000000u) ? ~b : (b | 0x80000000u);
}
__device__ __forceinline__ float funmap(unsigned u) {
    unsigned b = (u & 0x80000000u) ? (u & 0x7fffffffu) : ~u;
    return __uint_as_float(b);
}

// ---------- CSR build ----------
__global__ void k_count(const int* __restrict__ dst, int* __restrict__ deg, int E) {
    int e = blockIdx.x * 256 + threadIdx.x;
    if (e < E) atomicAdd(&deg[dst[e]], 1);
}

__global__ void k_dis(const int* __restrict__ deg, float* __restrict__ dis, int N) {
    int i = blockIdx.x * 256 + threadIdx.x;
    if (i < N) dis[i] = rsqrtf((float)(deg[i] + 1));  // +1 = self loop
}

__global__ void k_scanA(const int* __restrict__ deg, int* __restrict__ rowst,
                        int* __restrict__ bsum, int N) {
    __shared__ int s[256];
    int i = blockIdx.x * 256 + threadIdx.x;
    int v = (i < N) ? deg[i] : 0;
    s[threadIdx.x] = v;
    __syncthreads();
    for (int off = 1; off < 256; off <<= 1) {
        int t = (threadIdx.x >= off) ? s[threadIdx.x - off] : 0;
        __syncthreads();
        s[threadIdx.x] += t;
        __syncthreads();
    }
    if (i < N) rowst[i] = s[threadIdx.x] - v;   // block-local exclusive
    if (threadIdx.x == 255) bsum[blockIdx.x] = s[255];
}

__global__ void k_scanB(int* __restrict__ bsum, int NB) {
    __shared__ int s[512];
    int t = threadIdx.x;
    int v = (t < NB) ? bsum[t] : 0;
    s[t] = v;
    __syncthreads();
    for (int off = 1; off < 512; off <<= 1) {
        int x = (t >= off) ? s[t - off] : 0;
        __syncthreads();
        s[t] += x;
        __syncthreads();
    }
    if (t < NB) bsum[t] = s[t] - v;             // exclusive
}

__global__ void k_scanC(int* __restrict__ rowst, const int* __restrict__ bsum, int N) {
    int i = blockIdx.x * 256 + threadIdx.x;
    if (i < N) rowst[i] += bsum[blockIdx.x];
}

__global__ void k_fill(const int* __restrict__ src, const int* __restrict__ dst,
                       const float* __restrict__ dis, const int* __restrict__ rowst,
                       int* __restrict__ cnt, int2* __restrict__ edge, int E) {
    int e = blockIdx.x * 256 + threadIdx.x;
    if (e >= E) return;
    int d = dst[e], s = src[e];
    int p = rowst[d] + atomicAdd(&cnt[d], 1);
    edge[p] = make_int2(s, __float_as_int(dis[s] * dis[d]));
}

// ---------- encoder: out = relu(prop(x)@W1+b1)@W2 ----------
// wave per node; W1 in registers, W2 in LDS; no __syncthreads in the loop
__global__ __launch_bounds__(256) void k_enc(
        const float* __restrict__ x, float* __restrict__ out,
        const float* __restrict__ dis, const int* __restrict__ rowst,
        const int* __restrict__ deg, const int2* __restrict__ edge,
        const float* __restrict__ W1, const float* __restrict__ b1,
        const float* __restrict__ W2, int N) {
    __shared__ float W2l[128 * 64];   // 32 KB
    int t = threadIdx.x, lane = t & 63, w = t >> 6;
    for (int i = t; i < 128 * 64 / 4; i += 256)
        ((float4*)W2l)[i] = ((const float4*)W2)[i];
    __syncthreads();
    // per-lane constants
    float w1a[16], w1b[16];
    #pragma unroll
    for (int k = 0; k < 16; ++k) {
        w1a[k] = W1[k * 128 + lane];
        w1b[k] = W1[k * 128 + lane + 64];
    }
    float b1a = b1[lane], b1b = b1[lane + 64];
    int qq = lane & 3, e = lane >> 2;          // 16 edge groups x 4 lanes (float4)
    const float4* x4 = (const float4*)x;
    const int wstride = gridDim.x * 4;
    for (int node = blockIdx.x * 4 + w; node < N; node += wstride) {
        float d = dis[node];
        float sc = d * d * (1.f / 16.f);       // self-loop spread over 16 groups
        float4 sf = x4[node * 4 + qq];
        float ax = sf.x * sc, ay = sf.y * sc, az = sf.z * sc, aw = sf.w * sc;
        int s = rowst[node], dg = deg[node];
        const int2* ep = edge + s;
        int i = e;
        for (; i + 16 < dg; i += 32) {         // unroll x2: edges i, i+16
            int2 e0 = ep[i], e1 = ep[i + 16];
            float4 r0 = x4[e0.x * 4 + qq];
            float4 r1 = x4[e1.x * 4 + qq];
            float w0 = __int_as_float(e0.y), w1 = __int_as_float(e1.y);
            ax += w0 * r0.x; ay += w0 * r0.y; az += w0 * r0.z; aw += w0 * r0.w;
            ax += w1 * r1.x; ay += w1 * r1.y; az += w1 * r1.z; aw += w1 * r1.w;
        }
        if (i < dg) {
            int2 e0 = ep[i];
            float4 r0 = x4[e0.x * 4 + qq];
            float w0 = __int_as_float(e0.y);
            ax += w0 * r0.x; ay += w0 * r0.y; az += w0 * r0.z; aw += w0 * r0.w;
        }
        // reduce the 16 edge-groups (same qq class): xor 4,8,16,32
        ax += __shfl_xor(ax, 4);  ay += __shfl_xor(ay, 4);  az += __shfl_xor(az, 4);  aw += __shfl_xor(aw, 4);
        ax += __shfl_xor(ax, 8);  ay += __shfl_xor(ay, 8);  az += __shfl_xor(az, 8);  aw += __shfl_xor(aw, 8);
        ax += __shfl_xor(ax, 16); ay += __shfl_xor(ay, 16); az += __shfl_xor(az, 16); aw += __shfl_xor(aw, 16);
        ax += __shfl_xor(ax, 32); ay += __shfl_xor(ay, 32); az += __shfl_xor(az, 32); aw += __shfl_xor(aw, 32);
        // now lane L holds p[4*(L&3)+c] in (ax,ay,az,aw); p[k] = shfl(comp k&3, lane k>>2)
        float z0 = b1a, z1 = b1b;
        #pragma unroll
        for (int k = 0; k < 16; ++k) {
            float v = ((k & 3) == 0) ? ax : ((k & 3) == 1) ? ay : ((k & 3) == 2) ? az : aw;
            float pk = __shfl(v, k >> 2);
            z0 += pk * w1a[k];
            z1 += pk * w1b[k];
        }
        z0 = fmaxf(z0, 0.f);
        z1 = fmaxf(z1, 0.f);
        // y2 = z1@W2 via readlane broadcasts (compile-time lane index)
        float acc = 0.f;
        #pragma unroll
        for (int k = 0; k < 64; ++k)
            acc += __shfl(z0, k) * W2l[k * 64 + lane];
        #pragma unroll
        for (int k = 0; k < 64; ++k)
            acc += __shfl(z1, k) * W2l[(k + 64) * 64 + lane];
        out[node * 64 + lane] = acc;
    }
}

// ---------- prop64 (persistent, 2 nodes/wave): z = prop(in)+bias [relu]; out = W ? z@W(+gbias) : z
__global__ __launch_bounds__(256) void k_prop64(
        const float* __restrict__ in, float* __restrict__ out,
        const float* __restrict__ dis, const int* __restrict__ rowst,
        const int* __restrict__ deg, const int2* __restrict__ edge,
        const float* __restrict__ bias, int relu,
        const float* __restrict__ W, const float* __restrict__ gbias, int N) {
    __shared__ float Wlds[64 * 64];
    __shared__ float zbuf[4][2][64];
    int t = threadIdx.x, lane = t & 63, w = t >> 6;
    int q = lane & 15, g = lane >> 4;          // 4 edge groups x 16 lanes (float4)
    const float4* in4 = (const float4*)in;
    if (W) {
        for (int i = t; i < 64 * 64 / 4; i += 256)
            ((float4*)Wlds)[i] = ((const float4*)W)[i];
        __syncthreads();
    }
    float4 b4 = make_float4(0.f, 0.f, 0.f, 0.f);
    if (bias) b4 = ((const float4*)bias)[q];
    float gb = (W && gbias) ? gbias[lane] : 0.f;
    int wid = blockIdx.x * 4 + w;
    const int stride = gridDim.x * 4 * 2;
    for (int n0 = wid * 2; n0 < N; n0 += stride) {
        int n1 = n0 + 1;
        bool h1 = n1 < N;
        int s0 = rowst[n0], d0 = deg[n0];
        int s1 = h1 ? rowst[n1] : s0, d1 = h1 ? deg[n1] : 0;
        float di0 = dis[n0];
        float di1 = h1 ? dis[n1] : 0.f;
        const int2* e0 = edge + s0;
        const int2* e1 = edge + s1;
        float4 sf0 = in4[n0 * 16 + q];
        float4 sf1 = h1 ? in4[n1 * 16 + q] : sf0;
        float sc0 = di0 * di0 * 0.25f, sc1 = di1 * di1 * 0.25f;
        float a0x = sf0.x*sc0, a0y = sf0.y*sc0, a0z = sf0.z*sc0, a0w = sf0.w*sc0;
        float a1x = sf1.x*sc1, a1y = sf1.y*sc1, a1z = sf1.z*sc1, a1w = sf1.w*sc1;
        int m = d0 > d1 ? d0 : d1;
        for (int base = 0; base < m; base += 8) {
            int i = base + g, j = base + g + 4;
            int2 m0a = e0[(i < d0) ? i : 0];
            int2 m0b = e0[(j < d0) ? j : 0];
            int2 m1a = e1[(i < d1) ? i : 0];
            int2 m1b = e1[(j < d1) ? j : 0];
            float4 r0a = in4[m0a.x * 16 + q];
            float4 r0b = in4[m0b.x * 16 + q];
            float4 r1a = in4[m1a.x * 16 + q];
            float4 r1b = in4[m1b.x * 16 + q];
            float w0a = (i < d0) ? __int_as_float(m0a.y) : 0.f;
            float w0b = (j < d0) ? __int_as_float(m0b.y) : 0.f;
            float w1a = (i < d1) ? __int_as_float(m1a.y) : 0.f;
            float w1b = (j < d1) ? __int_as_float(m1b.y) : 0.f;
            a0x += w0a*r0a.x; a0y += w0a*r0a.y; a0z += w0a*r0a.z; a0w += w0a*r0a.w;
            a0x += w0b*r0b.x; a0y += w0b*r0b.y; a0z += w0b*r0b.z; a0w += w0b*r0b.w;
            a1x += w1a*r1a.x; a1y += w1a*r1a.y; a1z += w1a*r1a.z; a1w += w1a*r1a.w;
            a1x += w1b*r1b.x; a1y += w1b*r1b.y; a1z += w1b*r1b.z; a1w += w1b*r1b.w;
        }
        // reduce the 4 edge-groups: xor 16, 32
        a0x += __shfl_xor(a0x,16); a0y += __shfl_xor(a0y,16); a0z += __shfl_xor(a0z,16); a0w += __shfl_xor(a0w,16);
        a0x += __shfl_xor(a0x,32); a0y += __shfl_xor(a0y,32); a0z += __shfl_xor(a0z,32); a0w += __shfl_xor(a0w,32);
        a1x += __shfl_xor(a1x,16); a1y += __shfl_xor(a1y,16); a1z += __shfl_xor(a1z,16); a1w += __shfl_xor(a1w,16);
        a1x += __shfl_xor(a1x,32); a1y += __shfl_xor(a1y,32); a1z += __shfl_xor(a1z,32); a1w += __shfl_xor(a1w,32);
        a0x += b4.x; a0y += b4.y; a0z += b4.z; a0w += b4.w;
        a1x += b4.x; a1y += b4.y; a1z += b4.z; a1w += b4.w;
        if (relu) {
            a0x = fmaxf(a0x,0.f); a0y = fmaxf(a0y,0.f); a0z = fmaxf(a0z,0.f); a0w = fmaxf(a0w,0.f);
            a1x = fmaxf(a1x,0.f); a1y = fmaxf(a1y,0.f); a1z = fmaxf(a1z,0.f); a1w = fmaxf(a1w,0.f);
        }
        if (!W) {
            if (g == 0) {
                ((float4*)out)[n0 * 16 + q] = make_float4(a0x, a0y, a0z, a0w);
                if (h1) ((float4*)out)[n1 * 16 + q] = make_float4(a1x, a1y, a1z, a1w);
            }
        } else {
            if (g == 0) {
                ((float4*)zbuf[w][0])[q] = make_float4(a0x, a0y, a0z, a0w);
                ((float4*)zbuf[w][1])[q] = make_float4(a1x, a1y, a1z, a1w);
            }
            // wave-local LDS RAW: in-order per wave, compiler inserts lgkmcnt wait
            float acc0 = gb, acc1 = gb;
            for (int k = 0; k < 64; ++k) {
                float wk = Wlds[k * 64 + lane];
                acc0 += zbuf[w][0][k] * wk;
                acc1 += zbuf[w][1][k] * wk;
            }
            out[n0 * 64 + lane] = acc0;
            if (h1) out[n1 * 64 + lane] = acc1;
        }
    }
}

// ---------- pooling + head ----------
__global__ void k_pool_init(unsigned* __restrict__ gmax) {
    gmax[blockIdx.x * 64 + threadIdx.x] = fmap(-INFINITY);
}

__global__ void k_pool(const float* __restrict__ z, const int* __restrict__ batch,
                       unsigned* __restrict__ gmax, int N) {
    int f = threadIdx.x & 63, w = threadIdx.x >> 6;
    int base = (blockIdx.x * 4 + w) * 32;
    if (base >= N) return;
    int end = base + 32; if (end > N) end = N;
    int b0 = batch[base], b1 = batch[end - 1];
    if (b0 == b1) {                            // fast path: single graph in window
        float lmax = -INFINITY;
        for (int n = base; n < end; ++n)
            lmax = fmaxf(lmax, z[n * 64 + f]);
        atomicMax(&gmax[b0 * 64 + f], fmap(lmax));
    } else {
        int curb = b0; float lmax = -INFINITY;
        for (int n = base; n < end; ++n) {
            int b = batch[n];
            if (b != curb) {
                atomicMax(&gmax[curb * 64 + f], fmap(lmax));
                curb = b; lmax = -INFINITY;
            }
            lmax = fmaxf(lmax, z[n * 64 + f]);
        }
        atomicMax(&gmax[curb * 64 + f], fmap(lmax));
    }
}

__global__ void k_head(const unsigned* __restrict__ gmax,
                       const float* __restrict__ Wf1, const float* __restrict__ bf1,
                       const float* __restrict__ Wf2, const float* __restrict__ bf2,
                       const float* __restrict__ Wc, const float* __restrict__ bc,
                       const float* __restrict__ Wcb, const float* __restrict__ bcb,
                       float* __restrict__ out) {
    __shared__ float g[8][64], h1[8][32], h2[8][16];
    int t = threadIdx.x;  // 64 threads
    for (int i = t; i < 512; i += 64) g[i >> 6][i & 63] = funmap(gmax[i]);
    __syncthreads();
    for (int i = t; i < 256; i += 64) {
        int r = i >> 5, c = i & 31;
        float a = bf1[c];
        for (int k = 0; k < 64; ++k) a += g[r][k] * Wf1[k * 32 + c];
        h1[r][c] = fmaxf(a, 0.f);
    }
    __syncthreads();
    for (int i = t; i < 128; i += 64) {
        int r = i >> 4, c = i & 15;
        float a = bf2[c];
        for (int k = 0; k < 32; ++k) a += h1[r][k] * Wf2[k * 16 + c];
        h2[r][c] = fmaxf(a, 0.f);
    }
    __syncthreads();
    if (t < 16) {
        int r = t & 7;
        bool comb = t >= 8;
        const float* W = comb ? Wcb : Wc;
        float a = comb ? bcb[0] : bc[0];
        for (int k = 0; k < 16; ++k) a += h2[r][k] * W[k];
        out[(comb ? 8 : 0) + r] = a;
    }
}

// ---------- launch ----------
extern "C" void kernel_launch(void* const* d_in, const int* in_sizes, int n_in,
                              void* d_out, int out_size, void* d_ws, size_t ws_size,
                              hipStream_t stream) {
    const float* x    = (const float*)d_in[0];
    const int*   ei   = (const int*)d_in[1];
    const int*   batch= (const int*)d_in[2];
    const float* W1   = (const float*)d_in[3];
    const float* b1   = (const float*)d_in[4];
    const float* W2   = (const float*)d_in[5];
    const float* b2   = (const float*)d_in[6];
    const float* Wg1  = (const float*)d_in[7];
    const float* bg1  = (const float*)d_in[8];
    const float* Wg2  = (const float*)d_in[9];
    const float* bg2  = (const float*)d_in[10];
    const float* Wg3  = (const float*)d_in[11];
    const float* bg3  = (const float*)d_in[12];
    const float* Wsg  = (const float*)d_in[13];
    const float* bsg  = (const float*)d_in[14];
    const float* Wf1  = (const float*)d_in[15];
    const float* bf1  = (const float*)d_in[16];
    const float* Wf2  = (const float*)d_in[17];
    const float* bf2  = (const float*)d_in[18];
    const float* Wc   = (const float*)d_in[19];
    const float* bc   = (const float*)d_in[20];
    const float* Wcb  = (const float*)d_in[21];
    const float* bcb  = (const float*)d_in[22];

    const int N = in_sizes[0] / 16;
    const int E = in_sizes[1] / 2;
    const int* esrc = ei;
    const int* edst = ei + E;

    char* ws = (char*)d_ws;
    auto alloc = [&](size_t bytes) -> char* {
        char* p = ws;
        ws += (bytes + 255) & ~(size_t)255;
        return p;
    };
    int*      deg   = (int*)alloc((size_t)N * 4);
    int*      cnt   = (int*)alloc((size_t)N * 4);
    int*      rowst = (int*)alloc((size_t)(N + 1) * 4);
    int*      bsum  = (int*)alloc(4096);
    float*    dis   = (float*)alloc((size_t)N * 4);
    int2*     edge  = (int2*)alloc((size_t)(E + 16) * 8);
    float*    bufA  = (float*)alloc((size_t)N * 64 * 4);
    float*    bufB  = (float*)alloc((size_t)N * 64 * 4);
    unsigned* gmax  = (unsigned*)alloc((size_t)G_GRAPHS * 64 * 4);

    hipMemsetAsync(deg, 0, (size_t)N * 4, stream);
    hipMemsetAsync(cnt, 0, (size_t)N * 4, stream);
    hipMemsetAsync(edge + E, 0, 16 * 8, stream);   // zero pad for clamped loads

    const int EB = (E + 255) / 256;
    const int NB = (N + 255) / 256;
    const int PB = 2048;   // persistent prop blocks
    const int CB = 1280;   // persistent enc blocks (5/CU, 32KB LDS)

    k_count<<<EB, 256, 0, stream>>>(edst, deg, E);
    k_dis<<<NB, 256, 0, stream>>>(deg, dis, N);
    k_scanA<<<NB, 256, 0, stream>>>(deg, rowst, bsum, N);
    k_scanB<<<1, 512, 0, stream>>>(bsum, NB);
    k_scanC<<<NB, 256, 0, stream>>>(rowst, bsum, N);
    k_fill<<<EB, 256, 0, stream>>>(esrc, edst, dis, rowst, cnt, edge, E);

    // encoder: y2 = relu(prop(x)@W1+b1)@W2
    k_enc<<<CB, 256, 0, stream>>>(x, bufA, dis, rowst, deg, edge, W1, b1, W2, N);
    // z2 = prop(y2)+b2; out = z2@Wg1
    k_prop64<<<PB, 256, 0, stream>>>(bufA, bufB, dis, rowst, deg, edge, b2, 0, Wg1, nullptr, N);
    // z3 = relu(prop(.)+bg1); out = z3@Wg2
    k_prop64<<<PB, 256, 0, stream>>>(bufB, bufA, dis, rowst, deg, edge, bg1, 1, Wg2, nullptr, N);
    // z4 = relu(prop(.)+bg2); out = z4@Wg3
    k_prop64<<<PB, 256, 0, stream>>>(bufA, bufB, dis, rowst, deg, edge, bg2, 1, Wg3, nullptr, N);
    // z5 = relu(prop(.)+bg3)
    k_prop64<<<PB, 256, 0, stream>>>(bufB, bufA, dis, rowst, deg, edge, bg3, 1, nullptr, nullptr, N);
    // SGConv: 3 plain props, then prop + @Wsg + bsg
    k_prop64<<<PB, 256, 0, stream>>>(bufA, bufB, dis, rowst, deg, edge, nullptr, 0, nullptr, nullptr, N);
    k_prop64<<<PB, 256, 0, stream>>>(bufB, bufA, dis, rowst, deg, edge, nullptr, 0, nullptr, nullptr, N);
    k_prop64<<<PB, 256, 0, stream>>>(bufA, bufB, dis, rowst, deg, edge, nullptr, 0, nullptr, nullptr, N);
    k_prop64<<<PB, 256, 0, stream>>>(bufB, bufA, dis, rowst, deg, edge, nullptr, 0, Wsg, bsg, N);

    // pool + head
    k_pool_init<<<G_GRAPHS, 64, 0, stream>>>(gmax);
    k_pool<<<(N + 127) / 128, 256, 0, stream>>>(bufA, batch, gmax, N);
    k_head<<<1, 64, 0, stream>>>(gmax, Wf1, bf1, Wf2, bf2, Wc, bc, Wcb, bcb, (float*)d_out);
}

// Round 7
// 712.043 us; speedup vs baseline: 1.2832x; 1.2832x over previous
//
#include <hip/hip_runtime.h>
#include <hip/hip_bf16.h>
#include <math.h>

#define G_GRAPHS 8

// ---------- helpers ----------
__device__ __forceinline__ unsigned fmap(float f) {
    unsigned b = __float_as_uint(f);
    return (b & 0x80000000u) ? ~b : (b | 0x80000000u);
}
__device__ __forceinline__ float funmap(unsigned u) {
    unsigned b = (u & 0x80000000u) ? (u & 0x7fffffffu) : ~u;
    return __uint_as_float(b);
}

// ---------- CSR build ----------
__global__ void k_count(const int* __restrict__ dst, int* __restrict__ deg, int E) {
    int e = blockIdx.x * 256 + threadIdx.x;
    if (e < E) atomicAdd(&deg[dst[e]], 1);
}

__global__ void k_dis(const int* __restrict__ deg, float* __restrict__ dis, int N) {
    int i = blockIdx.x * 256 + threadIdx.x;
    if (i < N) dis[i] = rsqrtf((float)(deg[i] + 1));  // +1 = self loop
}

__global__ void k_scanA(const int* __restrict__ deg, int* __restrict__ rowst,
                        int* __restrict__ bsum, int N) {
    __shared__ int s[256];
    int i = blockIdx.x * 256 + threadIdx.x;
    int v = (i < N) ? deg[i] : 0;
    s[threadIdx.x] = v;
    __syncthreads();
    for (int off = 1; off < 256; off <<= 1) {
        int t = (threadIdx.x >= off) ? s[threadIdx.x - off] : 0;
        __syncthreads();
        s[threadIdx.x] += t;
        __syncthreads();
    }
    if (i < N) rowst[i] = s[threadIdx.x] - v;   // block-local exclusive
    if (threadIdx.x == 255) bsum[blockIdx.x] = s[255];
}

__global__ void k_scanB(int* __restrict__ bsum, int NB) {
    __shared__ int s[512];
    int t = threadIdx.x;
    int v = (t < NB) ? bsum[t] : 0;
    s[t] = v;
    __syncthreads();
    for (int off = 1; off < 512; off <<= 1) {
        int x = (t >= off) ? s[t - off] : 0;
        __syncthreads();
        s[t] += x;
        __syncthreads();
    }
    if (t < NB) bsum[t] = s[t] - v;             // exclusive
}

__global__ void k_scanC(int* __restrict__ rowst, const int* __restrict__ bsum, int N) {
    int i = blockIdx.x * 256 + threadIdx.x;
    if (i < N) rowst[i] += bsum[blockIdx.x];
}

__global__ void k_fill(const int* __restrict__ src, const int* __restrict__ dst,
                       const float* __restrict__ dis, const int* __restrict__ rowst,
                       int* __restrict__ cnt, int2* __restrict__ edge, int E) {
    int e = blockIdx.x * 256 + threadIdx.x;
    if (e >= E) return;
    int d = dst[e], s = src[e];
    int p = rowst[d] + atomicAdd(&cnt[d], 1);
    edge[p] = make_int2(s, __float_as_int(dis[s] * dis[d]));
}

// ---------- prop16: p0 = prop(x), dim 16; 4 lanes/node, 16 nodes/wave ----------
__global__ __launch_bounds__(256) void k_prop16(
        const float* __restrict__ x, float* __restrict__ out,
        const float* __restrict__ dis, const int* __restrict__ rowst,
        const int* __restrict__ deg, const int2* __restrict__ edge, int N) {
    int t = threadIdx.x, lane = t & 63, w = t >> 6;
    int grp = lane >> 2, sub = lane & 3;
    int node = blockIdx.x * 64 + w * 16 + grp;
    if (node >= N) return;
    const float4* x4 = (const float4*)x;
    float d = dis[node];
    float4 sf = x4[node * 4 + sub];
    float sc = d * d;
    float ax = sf.x * sc, ay = sf.y * sc, az = sf.z * sc, aw = sf.w * sc;
    int s = rowst[node], dg = deg[node];
    const int2* ep = edge + s;
    int i = 0;
    for (; i + 1 < dg; i += 2) {
        int2 e0 = ep[i], e1 = ep[i + 1];
        float4 r0 = x4[e0.x * 4 + sub];
        float4 r1 = x4[e1.x * 4 + sub];
        float w0 = __int_as_float(e0.y), w1 = __int_as_float(e1.y);
        ax += w0 * r0.x; ay += w0 * r0.y; az += w0 * r0.z; aw += w0 * r0.w;
        ax += w1 * r1.x; ay += w1 * r1.y; az += w1 * r1.z; aw += w1 * r1.w;
    }
    if (i < dg) {
        int2 e0 = ep[i];
        float4 r0 = x4[e0.x * 4 + sub];
        float w0 = __int_as_float(e0.y);
        ax += w0 * r0.x; ay += w0 * r0.y; az += w0 * r0.z; aw += w0 * r0.w;
    }
    ((float4*)out)[node * 4 + sub] = make_float4(ax, ay, az, aw);
}

// ---------- dense: y2 = relu(p0@W1+b1)@W2; wave per 4-node quad ----------
__global__ __launch_bounds__(256) void k_dense(
        const float* __restrict__ p0, float* __restrict__ out,
        const float* __restrict__ W1, const float* __restrict__ b1,
        const float* __restrict__ W2, int N) {
    __shared__ float zT[4][128][4];   // [wave][feat][node-in-quad]
    int t = threadIdx.x, lane = t & 63, w = t >> 6;
    int base = (blockIdx.x * 4 + w) * 4;   // first node of quad
    if (base >= N) return;
    // lane L holds p0[node base+(L>>4)][feat L&15]
    float p = p0[base * 16 + lane];
    // z1 halves: lane = feature f and f+64
    float z0a = b1[lane], z1a = z0a;  // init below properly per j
    float zA[4], zB[4];
    float bA = b1[lane], bB = b1[lane + 64];
    #pragma unroll
    for (int j = 0; j < 4; ++j) { zA[j] = bA; zB[j] = bB; }
    #pragma unroll
    for (int k = 0; k < 16; ++k) {
        float w1a = W1[k * 128 + lane];
        float w1b = W1[k * 128 + lane + 64];
        #pragma unroll
        for (int j = 0; j < 4; ++j) {
            float pk = __shfl(p, j * 16 + k);
            zA[j] += pk * w1a;
            zB[j] += pk * w1b;
        }
    }
    #pragma unroll
    for (int j = 0; j < 4; ++j) {
        zT[w][lane][j]      = fmaxf(zA[j], 0.f);
        zT[w][lane + 64][j] = fmaxf(zB[j], 0.f);
    }
    // wave-local LDS RAW; in-order per wave
    float acc[4] = {0.f, 0.f, 0.f, 0.f};
    #pragma unroll 4
    for (int k = 0; k < 128; ++k) {
        float wk = W2[k * 64 + lane];
        float4 zk = *(const float4*)&zT[w][k][0];
        acc[0] += zk.x * wk; acc[1] += zk.y * wk;
        acc[2] += zk.z * wk; acc[3] += zk.w * wk;
    }
    #pragma unroll
    for (int j = 0; j < 4; ++j)
        if (base + j < N) out[(base + j) * 64 + lane] = acc[j];
}

// ---------- prop64 (persistent, 2 nodes/wave): z = prop(in)+bias [relu]; out = W ? z@W(+gbias) : z
__global__ __launch_bounds__(256) void k_prop64(
        const float* __restrict__ in, float* __restrict__ out,
        const float* __restrict__ dis, const int* __restrict__ rowst,
        const int* __restrict__ deg, const int2* __restrict__ edge,
        const float* __restrict__ bias, int relu,
        const float* __restrict__ W, const float* __restrict__ gbias, int N) {
    __shared__ float Wlds[64 * 64];
    __shared__ float zbuf[4][2][64];
    int t = threadIdx.x, lane = t & 63, w = t >> 6;
    int q = lane & 15, g = lane >> 4;          // 4 edge groups x 16 lanes (float4)
    const float4* in4 = (const float4*)in;
    if (W) {
        for (int i = t; i < 64 * 64 / 4; i += 256)
            ((float4*)Wlds)[i] = ((const float4*)W)[i];
        __syncthreads();
    }
    float4 b4 = make_float4(0.f, 0.f, 0.f, 0.f);
    if (bias) b4 = ((const float4*)bias)[q];
    float gb = (W && gbias) ? gbias[lane] : 0.f;
    int wid = blockIdx.x * 4 + w;
    const int stride = gridDim.x * 4 * 2;
    for (int n0 = wid * 2; n0 < N; n0 += stride) {
        int n1 = n0 + 1;
        bool h1 = n1 < N;
        int s0 = rowst[n0], d0 = deg[n0];
        int s1 = h1 ? rowst[n1] : s0, d1 = h1 ? deg[n1] : 0;
        float di0 = dis[n0];
        float di1 = h1 ? dis[n1] : 0.f;
        const int2* e0 = edge + s0;
        const int2* e1 = edge + s1;
        float4 sf0 = in4[n0 * 16 + q];
        float4 sf1 = h1 ? in4[n1 * 16 + q] : sf0;
        float sc0 = di0 * di0 * 0.25f, sc1 = di1 * di1 * 0.25f;
        float a0x = sf0.x*sc0, a0y = sf0.y*sc0, a0z = sf0.z*sc0, a0w = sf0.w*sc0;
        float a1x = sf1.x*sc1, a1y = sf1.y*sc1, a1z = sf1.z*sc1, a1w = sf1.w*sc1;
        int m = d0 > d1 ? d0 : d1;
        for (int base = 0; base < m; base += 8) {
            int i = base + g, j = base + g + 4;
            int2 m0a = e0[(i < d0) ? i : 0];
            int2 m0b = e0[(j < d0) ? j : 0];
            int2 m1a = e1[(i < d1) ? i : 0];
            int2 m1b = e1[(j < d1) ? j : 0];
            float4 r0a = in4[m0a.x * 16 + q];
            float4 r0b = in4[m0b.x * 16 + q];
            float4 r1a = in4[m1a.x * 16 + q];
            float4 r1b = in4[m1b.x * 16 + q];
            float w0a = (i < d0) ? __int_as_float(m0a.y) : 0.f;
            float w0b = (j < d0) ? __int_as_float(m0b.y) : 0.f;
            float w1a = (i < d1) ? __int_as_float(m1a.y) : 0.f;
            float w1b = (j < d1) ? __int_as_float(m1b.y) : 0.f;
            a0x += w0a*r0a.x; a0y += w0a*r0a.y; a0z += w0a*r0a.z; a0w += w0a*r0a.w;
            a0x += w0b*r0b.x; a0y += w0b*r0b.y; a0z += w0b*r0b.z; a0w += w0b*r0b.w;
            a1x += w1a*r1a.x; a1y += w1a*r1a.y; a1z += w1a*r1a.z; a1w += w1a*r1a.w;
            a1x += w1b*r1b.x; a1y += w1b*r1b.y; a1z += w1b*r1b.z; a1w += w1b*r1b.w;
        }
        // reduce the 4 edge-groups: xor 16, 32
        a0x += __shfl_xor(a0x,16); a0y += __shfl_xor(a0y,16); a0z += __shfl_xor(a0z,16); a0w += __shfl_xor(a0w,16);
        a0x += __shfl_xor(a0x,32); a0y += __shfl_xor(a0y,32); a0z += __shfl_xor(a0z,32); a0w += __shfl_xor(a0w,32);
        a1x += __shfl_xor(a1x,16); a1y += __shfl_xor(a1y,16); a1z += __shfl_xor(a1z,16); a1w += __shfl_xor(a1w,16);
        a1x += __shfl_xor(a1x,32); a1y += __shfl_xor(a1y,32); a1z += __shfl_xor(a1z,32); a1w += __shfl_xor(a1w,32);
        a0x += b4.x; a0y += b4.y; a0z += b4.z; a0w += b4.w;
        a1x += b4.x; a1y += b4.y; a1z += b4.z; a1w += b4.w;
        if (relu) {
            a0x = fmaxf(a0x,0.f); a0y = fmaxf(a0y,0.f); a0z = fmaxf(a0z,0.f); a0w = fmaxf(a0w,0.f);
            a1x = fmaxf(a1x,0.f); a1y = fmaxf(a1y,0.f); a1z = fmaxf(a1z,0.f); a1w = fmaxf(a1w,0.f);
        }
        if (!W) {
            if (g == 0) {
                ((float4*)out)[n0 * 16 + q] = make_float4(a0x, a0y, a0z, a0w);
                if (h1) ((float4*)out)[n1 * 16 + q] = make_float4(a1x, a1y, a1z, a1w);
            }
        } else {
            if (g == 0) {
                ((float4*)zbuf[w][0])[q] = make_float4(a0x, a0y, a0z, a0w);
                ((float4*)zbuf[w][1])[q] = make_float4(a1x, a1y, a1z, a1w);
            }
            // wave-local LDS RAW: in-order per wave
            float acc0 = gb, acc1 = gb;
            for (int k = 0; k < 64; ++k) {
                float wk = Wlds[k * 64 + lane];
                acc0 += zbuf[w][0][k] * wk;
                acc1 += zbuf[w][1][k] * wk;
            }
            out[n0 * 64 + lane] = acc0;
            if (h1) out[n1 * 64 + lane] = acc1;
        }
    }
}

// ---------- pooling + head ----------
__global__ void k_pool_init(unsigned* __restrict__ gmax) {
    gmax[blockIdx.x * 64 + threadIdx.x] = fmap(-INFINITY);
}

__global__ void k_pool(const float* __restrict__ z, const int* __restrict__ batch,
                       unsigned* __restrict__ gmax, int N) {
    int f = threadIdx.x & 63, w = threadIdx.x >> 6;
    int base = (blockIdx.x * 4 + w) * 32;
    if (base >= N) return;
    int end = base + 32; if (end > N) end = N;
    int b0 = batch[base], b1 = batch[end - 1];
    if (b0 == b1) {                            // fast path: single graph in window
        float lmax = -INFINITY;
        for (int n = base; n < end; ++n)
            lmax = fmaxf(lmax, z[n * 64 + f]);
        atomicMax(&gmax[b0 * 64 + f], fmap(lmax));
    } else {
        int curb = b0; float lmax = -INFINITY;
        for (int n = base; n < end; ++n) {
            int b = batch[n];
            if (b != curb) {
                atomicMax(&gmax[curb * 64 + f], fmap(lmax));
                curb = b; lmax = -INFINITY;
            }
            lmax = fmaxf(lmax, z[n * 64 + f]);
        }
        atomicMax(&gmax[curb * 64 + f], fmap(lmax));
    }
}

__global__ void k_head(const unsigned* __restrict__ gmax,
                       const float* __restrict__ Wf1, const float* __restrict__ bf1,
                       const float* __restrict__ Wf2, const float* __restrict__ bf2,
                       const float* __restrict__ Wc, const float* __restrict__ bc,
                       const float* __restrict__ Wcb, const float* __restrict__ bcb,
                       float* __restrict__ out) {
    __shared__ float g[8][64], h1[8][32], h2[8][16];
    int t = threadIdx.x;  // 64 threads
    for (int i = t; i < 512; i += 64) g[i >> 6][i & 63] = funmap(gmax[i]);
    __syncthreads();
    for (int i = t; i < 256; i += 64) {
        int r = i >> 5, c = i & 31;
        float a = bf1[c];
        for (int k = 0; k < 64; ++k) a += g[r][k] * Wf1[k * 32 + c];
        h1[r][c] = fmaxf(a, 0.f);
    }
    __syncthreads();
    for (int i = t; i < 128; i += 64) {
        int r = i >> 4, c = i & 15;
        float a = bf2[c];
        for (int k = 0; k < 32; ++k) a += h1[r][k] * Wf2[k * 16 + c];
        h2[r][c] = fmaxf(a, 0.f);
    }
    __syncthreads();
    if (t < 16) {
        int r = t & 7;
        bool comb = t >= 8;
        const float* W = comb ? Wcb : Wc;
        float a = comb ? bcb[0] : bc[0];
        for (int k = 0; k < 16; ++k) a += h2[r][k] * W[k];
        out[(comb ? 8 : 0) + r] = a;
    }
}

// ---------- launch ----------
extern "C" void kernel_launch(void* const* d_in, const int* in_sizes, int n_in,
                              void* d_out, int out_size, void* d_ws, size_t ws_size,
                              hipStream_t stream) {
    const float* x    = (const float*)d_in[0];
    const int*   ei   = (const int*)d_in[1];
    const int*   batch= (const int*)d_in[2];
    const float* W1   = (const float*)d_in[3];
    const float* b1   = (const float*)d_in[4];
    const float* W2   = (const float*)d_in[5];
    const float* b2   = (const float*)d_in[6];
    const float* Wg1  = (const float*)d_in[7];
    const float* bg1  = (const float*)d_in[8];
    const float* Wg2  = (const float*)d_in[9];
    const float* bg2  = (const float*)d_in[10];
    const float* Wg3  = (const float*)d_in[11];
    const float* bg3  = (const float*)d_in[12];
    const float* Wsg  = (const float*)d_in[13];
    const float* bsg  = (const float*)d_in[14];
    const float* Wf1  = (const float*)d_in[15];
    const float* bf1  = (const float*)d_in[16];
    const float* Wf2  = (const float*)d_in[17];
    const float* bf2  = (const float*)d_in[18];
    const float* Wc   = (const float*)d_in[19];
    const float* bc   = (const float*)d_in[20];
    const float* Wcb  = (const float*)d_in[21];
    const float* bcb  = (const float*)d_in[22];

    const int N = in_sizes[0] / 16;
    const int E = in_sizes[1] / 2;
    const int* esrc = ei;
    const int* edst = ei + E;

    char* ws = (char*)d_ws;
    auto alloc = [&](size_t bytes) -> char* {
        char* p = ws;
        ws += (bytes + 255) & ~(size_t)255;
        return p;
    };
    int*      deg   = (int*)alloc((size_t)N * 4);
    int*      cnt   = (int*)alloc((size_t)N * 4);
    int*      rowst = (int*)alloc((size_t)(N + 1) * 4);
    int*      bsum  = (int*)alloc(4096);
    float*    dis   = (float*)alloc((size_t)N * 4);
    int2*     edge  = (int2*)alloc((size_t)(E + 16) * 8);
    float*    p0    = (float*)alloc((size_t)N * 16 * 4);
    float*    bufA  = (float*)alloc((size_t)N * 64 * 4);
    float*    bufB  = (float*)alloc((size_t)N * 64 * 4);
    unsigned* gmax  = (unsigned*)alloc((size_t)G_GRAPHS * 64 * 4);

    hipMemsetAsync(deg, 0, (size_t)N * 4, stream);
    hipMemsetAsync(cnt, 0, (size_t)N * 4, stream);
    hipMemsetAsync(edge + E, 0, 16 * 8, stream);   // zero pad for clamped loads

    const int EB = (E + 255) / 256;
    const int NB = (N + 255) / 256;
    const int PB = 2048;   // persistent prop blocks

    k_count<<<EB, 256, 0, stream>>>(edst, deg, E);
    k_dis<<<NB, 256, 0, stream>>>(deg, dis, N);
    k_scanA<<<NB, 256, 0, stream>>>(deg, rowst, bsum, N);
    k_scanB<<<1, 512, 0, stream>>>(bsum, NB);
    k_scanC<<<NB, 256, 0, stream>>>(rowst, bsum, N);
    k_fill<<<EB, 256, 0, stream>>>(esrc, edst, dis, rowst, cnt, edge, E);

    // encoder: p0 = prop(x); y2 = relu(p0@W1+b1)@W2
    k_prop16<<<(N + 63) / 64, 256, 0, stream>>>(x, p0, dis, rowst, deg, edge, N);
    k_dense<<<(N + 15) / 16, 256, 0, stream>>>(p0, bufA, W1, b1, W2, N);
    // z2 = prop(y2)+b2; out = z2@Wg1
    k_prop64<<<PB, 256, 0, stream>>>(bufA, bufB, dis, rowst, deg, edge, b2, 0, Wg1, nullptr, N);
    // z3 = relu(prop(.)+bg1); out = z3@Wg2
    k_prop64<<<PB, 256, 0, stream>>>(bufB, bufA, dis, rowst, deg, edge, bg1, 1, Wg2, nullptr, N);
    // z4 = relu(prop(.)+bg2); out = z4@Wg3
    k_prop64<<<PB, 256, 0, stream>>>(bufA, bufB, dis, rowst, deg, edge, bg2, 1, Wg3, nullptr, N);
    // z5 = relu(prop(.)+bg3)
    k_prop64<<<PB, 256, 0, stream>>>(bufB, bufA, dis, rowst, deg, edge, bg3, 1, nullptr, nullptr, N);
    // SGConv: 3 plain props, then prop + @Wsg + bsg
    k_prop64<<<PB, 256, 0, stream>>>(bufA, bufB, dis, rowst, deg, edge, nullptr, 0, nullptr, nullptr, N);
    k_prop64<<<PB, 256, 0, stream>>>(bufB, bufA, dis, rowst, deg, edge, nullptr, 0, nullptr, nullptr, N);
    k_prop64<<<PB, 256, 0, stream>>>(bufA, bufB, dis, rowst, deg, edge, nullptr, 0, nullptr, nullptr, N);
    k_prop64<<<PB, 256, 0, stream>>>(bufB, bufA, dis, rowst, deg, edge, nullptr, 0, Wsg, bsg, N);

    // pool + head
    k_pool_init<<<G_GRAPHS, 64, 0, stream>>>(gmax);
    k_pool<<<(N + 127) / 128, 256, 0, stream>>>(bufA, batch, gmax, N);
    k_head<<<1, 64, 0, stream>>>(gmax, Wf1, bf1, Wf2, bf2, Wc, bc, Wcb, bcb, (float*)d_out);
}

// Round 8
// 611.150 us; speedup vs baseline: 1.4950x; 1.1651x over previous
//
#include <hip/hip_runtime.h>
#include <hip/hip_bf16.h>
#include <hip/hip_fp16.h>
#include <math.h>

#define G_GRAPHS 8

// ---------- helpers ----------
__device__ __forceinline__ unsigned fmap(float f) {
    unsigned b = __float_as_uint(f);
    return (b & 0x80000000u) ? ~b : (b | 0x80000000u);
}
__device__ __forceinline__ float funmap(unsigned u) {
    unsigned b = (u & 0x80000000u) ? (u & 0x7fffffffu) : ~u;
    return __uint_as_float(b);
}
__device__ __forceinline__ void fma_row(float wv, uint2 r,
                                        float& ax, float& ay, float& az, float& aw) {
    float2 f01 = __half22float2(*(__half2*)&r.x);
    float2 f23 = __half22float2(*(__half2*)&r.y);
    ax += wv * f01.x; ay += wv * f01.y; az += wv * f23.x; aw += wv * f23.y;
}
__device__ __forceinline__ uint2 pack4(float ax, float ay, float az, float aw) {
    __half2 p01 = __float22half2_rn(make_float2(ax, ay));
    __half2 p23 = __float22half2_rn(make_float2(az, aw));
    uint2 r;
    r.x = *(unsigned*)&p01;
    r.y = *(unsigned*)&p23;
    return r;
}

// ---------- CSR build ----------
__global__ void k_count(const int* __restrict__ dst, int* __restrict__ deg, int E) {
    int e = blockIdx.x * 256 + threadIdx.x;
    if (e < E) atomicAdd(&deg[dst[e]], 1);
}

__global__ void k_dis(const int* __restrict__ deg, float* __restrict__ dis, int N) {
    int i = blockIdx.x * 256 + threadIdx.x;
    if (i < N) dis[i] = rsqrtf((float)(deg[i] + 1));  // +1 = self loop
}

__global__ void k_scanA(const int* __restrict__ deg, int* __restrict__ rowst,
                        int* __restrict__ bsum, int N) {
    __shared__ int s[256];
    int i = blockIdx.x * 256 + threadIdx.x;
    int v = (i < N) ? deg[i] : 0;
    s[threadIdx.x] = v;
    __syncthreads();
    for (int off = 1; off < 256; off <<= 1) {
        int t = (threadIdx.x >= off) ? s[threadIdx.x - off] : 0;
        __syncthreads();
        s[threadIdx.x] += t;
        __syncthreads();
    }
    if (i < N) rowst[i] = s[threadIdx.x] - v;   // block-local exclusive
    if (threadIdx.x == 255) bsum[blockIdx.x] = s[255];
}

__global__ void k_scanB(int* __restrict__ bsum, int NB) {
    __shared__ int s[512];
    int t = threadIdx.x;
    int v = (t < NB) ? bsum[t] : 0;
    s[t] = v;
    __syncthreads();
    for (int off = 1; off < 512; off <<= 1) {
        int x = (t >= off) ? s[t - off] : 0;
        __syncthreads();
        s[t] += x;
        __syncthreads();
    }
    if (t < NB) bsum[t] = s[t] - v;             // exclusive
}

__global__ void k_scanC(int* __restrict__ rowst, const int* __restrict__ bsum, int N) {
    int i = blockIdx.x * 256 + threadIdx.x;
    if (i < N) rowst[i] += bsum[blockIdx.x];
}

__global__ void k_fill(const int* __restrict__ src, const int* __restrict__ dst,
                       const float* __restrict__ dis, const int* __restrict__ rowst,
                       int* __restrict__ cnt, int2* __restrict__ edge, int E) {
    int e = blockIdx.x * 256 + threadIdx.x;
    if (e >= E) return;
    int d = dst[e], s = src[e];
    int p = rowst[d] + atomicAdd(&cnt[d], 1);
    edge[p] = make_int2(s, __float_as_int(dis[s] * dis[d]));
}

// ---------- x -> fp16 copy ----------
__global__ void k_x2h(const float* __restrict__ x, __half* __restrict__ xh, int n4) {
    int i = blockIdx.x * 256 + threadIdx.x;   // one float4 per thread
    if (i >= n4) return;
    float4 v = ((const float4*)x)[i];
    ((uint2*)xh)[i] = pack4(v.x, v.y, v.z, v.w);
}

// ---------- prop16: p0 = prop(x) dim16 (fp16 rows, fp32 out); 4 lanes/node ----------
__global__ __launch_bounds__(256) void k_prop16(
        const __half* __restrict__ xh, float* __restrict__ out,
        const float* __restrict__ dis, const int* __restrict__ rowst,
        const int* __restrict__ deg, const int2* __restrict__ edge, int N) {
    int t = threadIdx.x, lane = t & 63, w = t >> 6;
    int grp = lane >> 2, sub = lane & 3;
    int node = blockIdx.x * 64 + w * 16 + grp;
    if (node >= N) return;
    const uint2* xr = (const uint2*)xh;        // row = 4 uint2 (32 B)
    float d = dis[node];
    float sc = d * d;
    float ax = 0.f, ay = 0.f, az = 0.f, aw = 0.f;
    fma_row(sc, xr[node * 4 + sub], ax, ay, az, aw);
    int s = rowst[node], dg = deg[node];
    const int2* ep = edge + s;
    int i = 0;
    for (; i + 3 < dg; i += 4) {
        int2 e0 = ep[i], e1 = ep[i + 1], e2 = ep[i + 2], e3 = ep[i + 3];
        uint2 r0 = xr[e0.x * 4 + sub];
        uint2 r1 = xr[e1.x * 4 + sub];
        uint2 r2 = xr[e2.x * 4 + sub];
        uint2 r3 = xr[e3.x * 4 + sub];
        fma_row(__int_as_float(e0.y), r0, ax, ay, az, aw);
        fma_row(__int_as_float(e1.y), r1, ax, ay, az, aw);
        fma_row(__int_as_float(e2.y), r2, ax, ay, az, aw);
        fma_row(__int_as_float(e3.y), r3, ax, ay, az, aw);
    }
    for (; i < dg; ++i) {
        int2 e0 = ep[i];
        fma_row(__int_as_float(e0.y), xr[e0.x * 4 + sub], ax, ay, az, aw);
    }
    ((float4*)out)[node * 4 + sub] = make_float4(ax, ay, az, aw);
}

// ---------- dense: y2 = relu(p0@W1+b1)@W2 (fp32 in, fp16 out); wave per 4-node quad ----------
__global__ __launch_bounds__(256) void k_dense(
        const float* __restrict__ p0, __half* __restrict__ out,
        const float* __restrict__ W1, const float* __restrict__ b1,
        const float* __restrict__ W2, int N) {
    __shared__ float zT[4][128][4];   // [wave][feat][node-in-quad]
    int t = threadIdx.x, lane = t & 63, w = t >> 6;
    int base = (blockIdx.x * 4 + w) * 4;   // first node of quad
    if (base >= N) return;
    // lane L holds p0[node base+(L>>4)][feat L&15]
    float p = p0[base * 16 + lane];
    float zA[4], zB[4];
    float bA = b1[lane], bB = b1[lane + 64];
    #pragma unroll
    for (int j = 0; j < 4; ++j) { zA[j] = bA; zB[j] = bB; }
    #pragma unroll
    for (int k = 0; k < 16; ++k) {
        float w1a = W1[k * 128 + lane];
        float w1b = W1[k * 128 + lane + 64];
        #pragma unroll
        for (int j = 0; j < 4; ++j) {
            float pk = __shfl(p, j * 16 + k);
            zA[j] += pk * w1a;
            zB[j] += pk * w1b;
        }
    }
    #pragma unroll
    for (int j = 0; j < 4; ++j) {
        zT[w][lane][j]      = fmaxf(zA[j], 0.f);
        zT[w][lane + 64][j] = fmaxf(zB[j], 0.f);
    }
    // wave-local LDS RAW; in-order per wave
    float acc[4] = {0.f, 0.f, 0.f, 0.f};
    #pragma unroll 4
    for (int k = 0; k < 128; ++k) {
        float wk = W2[k * 64 + lane];
        float4 zk = *(const float4*)&zT[w][k][0];
        acc[0] += zk.x * wk; acc[1] += zk.y * wk;
        acc[2] += zk.z * wk; acc[3] += zk.w * wk;
    }
    #pragma unroll
    for (int j = 0; j < 4; ++j)
        if (base + j < N) out[(base + j) * 64 + lane] = __float2half(acc[j]);
}

// ---------- prop64 (persistent, 2 nodes/wave, fp16 rows): z = prop(in)+bias [relu]; out = W ? z@W(+gbias) : z
__global__ __launch_bounds__(256) void k_prop64(
        const __half* __restrict__ in, __half* __restrict__ out,
        const float* __restrict__ dis, const int* __restrict__ rowst,
        const int* __restrict__ deg, const int2* __restrict__ edge,
        const float* __restrict__ bias, int relu,
        const float* __restrict__ W, const float* __restrict__ gbias, int N) {
    __shared__ float Wlds[64 * 64];
    __shared__ float zbuf[4][2][64];
    int t = threadIdx.x, lane = t & 63, w = t >> 6;
    int q = lane & 15, g = lane >> 4;          // 4 edge groups x 16 lanes (uint2)
    const uint2* inr = (const uint2*)in;       // row = 16 uint2 (128 B)
    if (W) {
        for (int i = t; i < 64 * 64 / 4; i += 256)
            ((float4*)Wlds)[i] = ((const float4*)W)[i];
        __syncthreads();
    }
    float4 b4 = make_float4(0.f, 0.f, 0.f, 0.f);
    if (bias) b4 = ((const float4*)bias)[q];
    float gb = (W && gbias) ? gbias[lane] : 0.f;
    int wid = blockIdx.x * 4 + w;
    const int stride = gridDim.x * 4 * 2;
    for (int n0 = wid * 2; n0 < N; n0 += stride) {
        int n1 = n0 + 1;
        bool h1 = n1 < N;
        int s0 = rowst[n0], d0 = deg[n0];
        int s1 = h1 ? rowst[n1] : s0, d1 = h1 ? deg[n1] : 0;
        float di0 = dis[n0];
        float di1 = h1 ? dis[n1] : 0.f;
        const int2* e0 = edge + s0;
        const int2* e1 = edge + s1;
        float sc0 = di0 * di0 * 0.25f, sc1 = di1 * di1 * 0.25f;
        float a0x = 0.f, a0y = 0.f, a0z = 0.f, a0w = 0.f;
        float a1x = 0.f, a1y = 0.f, a1z = 0.f, a1w = 0.f;
        fma_row(sc0, inr[n0 * 16 + q], a0x, a0y, a0z, a0w);
        fma_row(sc1, inr[(h1 ? n1 : n0) * 16 + q], a1x, a1y, a1z, a1w);
        int m = d0 > d1 ? d0 : d1;
        for (int base = 0; base < m; base += 16) {
            int i0 = base + g, i1 = i0 + 4, i2 = i0 + 8, i3 = i0 + 12;
            // node 0: 4 edges
            int2 ma0 = e0[(i0 < d0) ? i0 : 0];
            int2 ma1 = e0[(i1 < d0) ? i1 : 0];
            int2 ma2 = e0[(i2 < d0) ? i2 : 0];
            int2 ma3 = e0[(i3 < d0) ? i3 : 0];
            // node 1: 4 edges
            int2 mb0 = e1[(i0 < d1) ? i0 : 0];
            int2 mb1 = e1[(i1 < d1) ? i1 : 0];
            int2 mb2 = e1[(i2 < d1) ? i2 : 0];
            int2 mb3 = e1[(i3 < d1) ? i3 : 0];
            uint2 ra0 = inr[ma0.x * 16 + q];
            uint2 ra1 = inr[ma1.x * 16 + q];
            uint2 ra2 = inr[ma2.x * 16 + q];
            uint2 ra3 = inr[ma3.x * 16 + q];
            uint2 rb0 = inr[mb0.x * 16 + q];
            uint2 rb1 = inr[mb1.x * 16 + q];
            uint2 rb2 = inr[mb2.x * 16 + q];
            uint2 rb3 = inr[mb3.x * 16 + q];
            float wa0 = (i0 < d0) ? __int_as_float(ma0.y) : 0.f;
            float wa1 = (i1 < d0) ? __int_as_float(ma1.y) : 0.f;
            float wa2 = (i2 < d0) ? __int_as_float(ma2.y) : 0.f;
            float wa3 = (i3 < d0) ? __int_as_float(ma3.y) : 0.f;
            float wb0 = (i0 < d1) ? __int_as_float(mb0.y) : 0.f;
            float wb1 = (i1 < d1) ? __int_as_float(mb1.y) : 0.f;
            float wb2 = (i2 < d1) ? __int_as_float(mb2.y) : 0.f;
            float wb3 = (i3 < d1) ? __int_as_float(mb3.y) : 0.f;
            fma_row(wa0, ra0, a0x, a0y, a0z, a0w);
            fma_row(wa1, ra1, a0x, a0y, a0z, a0w);
            fma_row(wa2, ra2, a0x, a0y, a0z, a0w);
            fma_row(wa3, ra3, a0x, a0y, a0z, a0w);
            fma_row(wb0, rb0, a1x, a1y, a1z, a1w);
            fma_row(wb1, rb1, a1x, a1y, a1z, a1w);
            fma_row(wb2, rb2, a1x, a1y, a1z, a1w);
            fma_row(wb3, rb3, a1x, a1y, a1z, a1w);
        }
        // reduce the 4 edge-groups: xor 16, 32
        a0x += __shfl_xor(a0x,16); a0y += __shfl_xor(a0y,16); a0z += __shfl_xor(a0z,16); a0w += __shfl_xor(a0w,16);
        a0x += __shfl_xor(a0x,32); a0y += __shfl_xor(a0y,32); a0z += __shfl_xor(a0z,32); a0w += __shfl_xor(a0w,32);
        a1x += __shfl_xor(a1x,16); a1y += __shfl_xor(a1y,16); a1z += __shfl_xor(a1z,16); a1w += __shfl_xor(a1w,16);
        a1x += __shfl_xor(a1x,32); a1y += __shfl_xor(a1y,32); a1z += __shfl_xor(a1z,32); a1w += __shfl_xor(a1w,32);
        a0x += b4.x; a0y += b4.y; a0z += b4.z; a0w += b4.w;
        a1x += b4.x; a1y += b4.y; a1z += b4.z; a1w += b4.w;
        if (relu) {
            a0x = fmaxf(a0x,0.f); a0y = fmaxf(a0y,0.f); a0z = fmaxf(a0z,0.f); a0w = fmaxf(a0w,0.f);
            a1x = fmaxf(a1x,0.f); a1y = fmaxf(a1y,0.f); a1z = fmaxf(a1z,0.f); a1w = fmaxf(a1w,0.f);
        }
        if (!W) {
            if (g == 0) {
                ((uint2*)out)[n0 * 16 + q] = pack4(a0x, a0y, a0z, a0w);
                if (h1) ((uint2*)out)[n1 * 16 + q] = pack4(a1x, a1y, a1z, a1w);
            }
        } else {
            if (g == 0) {
                ((float4*)zbuf[w][0])[q] = make_float4(a0x, a0y, a0z, a0w);
                ((float4*)zbuf[w][1])[q] = make_float4(a1x, a1y, a1z, a1w);
            }
            // wave-local LDS RAW: in-order per wave
            float acc0 = gb, acc1 = gb;
            for (int k = 0; k < 64; ++k) {
                float wk = Wlds[k * 64 + lane];
                acc0 += zbuf[w][0][k] * wk;
                acc1 += zbuf[w][1][k] * wk;
            }
            out[n0 * 64 + lane] = __float2half(acc0);
            if (h1) out[n1 * 64 + lane] = __float2half(acc1);
        }
    }
}

// ---------- pooling + head ----------
__global__ void k_pool_init(unsigned* __restrict__ gmax) {
    gmax[blockIdx.x * 64 + threadIdx.x] = fmap(-INFINITY);
}

__global__ void k_pool(const __half* __restrict__ z, const int* __restrict__ batch,
                       unsigned* __restrict__ gmax, int N) {
    int f = threadIdx.x & 63, w = threadIdx.x >> 6;
    int base = (blockIdx.x * 4 + w) * 32;
    if (base >= N) return;
    int end = base + 32; if (end > N) end = N;
    int b0 = batch[base], b1 = batch[end - 1];
    if (b0 == b1) {                            // fast path: single graph in window
        float lmax = -INFINITY;
        for (int n = base; n < end; ++n)
            lmax = fmaxf(lmax, __half2float(z[n * 64 + f]));
        atomicMax(&gmax[b0 * 64 + f], fmap(lmax));
    } else {
        int curb = b0; float lmax = -INFINITY;
        for (int n = base; n < end; ++n) {
            int b = batch[n];
            if (b != curb) {
                atomicMax(&gmax[curb * 64 + f], fmap(lmax));
                curb = b; lmax = -INFINITY;
            }
            lmax = fmaxf(lmax, __half2float(z[n * 64 + f]));
        }
        atomicMax(&gmax[curb * 64 + f], fmap(lmax));
    }
}

__global__ void k_head(const unsigned* __restrict__ gmax,
                       const float* __restrict__ Wf1, const float* __restrict__ bf1,
                       const float* __restrict__ Wf2, const float* __restrict__ bf2,
                       const float* __restrict__ Wc, const float* __restrict__ bc,
                       const float* __restrict__ Wcb, const float* __restrict__ bcb,
                       float* __restrict__ out) {
    __shared__ float g[8][64], h1[8][32], h2[8][16];
    int t = threadIdx.x;  // 64 threads
    for (int i = t; i < 512; i += 64) g[i >> 6][i & 63] = funmap(gmax[i]);
    __syncthreads();
    for (int i = t; i < 256; i += 64) {
        int r = i >> 5, c = i & 31;
        float a = bf1[c];
        for (int k = 0; k < 64; ++k) a += g[r][k] * Wf1[k * 32 + c];
        h1[r][c] = fmaxf(a, 0.f);
    }
    __syncthreads();
    for (int i = t; i < 128; i += 64) {
        int r = i >> 4, c = i & 15;
        float a = bf2[c];
        for (int k = 0; k < 32; ++k) a += h1[r][k] * Wf2[k * 16 + c];
        h2[r][c] = fmaxf(a, 0.f);
    }
    __syncthreads();
    if (t < 16) {
        int r = t & 7;
        bool comb = t >= 8;
        const float* W = comb ? Wcb : Wc;
        float a = comb ? bcb[0] : bc[0];
        for (int k = 0; k < 16; ++k) a += h2[r][k] * W[k];
        out[(comb ? 8 : 0) + r] = a;
    }
}

// ---------- launch ----------
extern "C" void kernel_launch(void* const* d_in, const int* in_sizes, int n_in,
                              void* d_out, int out_size, void* d_ws, size_t ws_size,
                              hipStream_t stream) {
    const float* x    = (const float*)d_in[0];
    const int*   ei   = (const int*)d_in[1];
    const int*   batch= (const int*)d_in[2];
    const float* W1   = (const float*)d_in[3];
    const float* b1   = (const float*)d_in[4];
    const float* W2   = (const float*)d_in[5];
    const float* b2   = (const float*)d_in[6];
    const float* Wg1  = (const float*)d_in[7];
    const float* bg1  = (const float*)d_in[8];
    const float* Wg2  = (const float*)d_in[9];
    const float* bg2  = (const float*)d_in[10];
    const float* Wg3  = (const float*)d_in[11];
    const float* bg3  = (const float*)d_in[12];
    const float* Wsg  = (const float*)d_in[13];
    const float* bsg  = (const float*)d_in[14];
    const float* Wf1  = (const float*)d_in[15];
    const float* bf1  = (const float*)d_in[16];
    const float* Wf2  = (const float*)d_in[17];
    const float* bf2  = (const float*)d_in[18];
    const float* Wc   = (const float*)d_in[19];
    const float* bc   = (const float*)d_in[20];
    const float* Wcb  = (const float*)d_in[21];
    const float* bcb  = (const float*)d_in[22];

    const int N = in_sizes[0] / 16;
    const int E = in_sizes[1] / 2;
    const int* esrc = ei;
    const int* edst = ei + E;

    char* ws = (char*)d_ws;
    auto alloc = [&](size_t bytes) -> char* {
        char* p = ws;
        ws += (bytes + 255) & ~(size_t)255;
        return p;
    };
    int*      deg   = (int*)alloc((size_t)N * 4);
    int*      cnt   = (int*)alloc((size_t)N * 4);
    int*      rowst = (int*)alloc((size_t)(N + 1) * 4);
    int*      bsum  = (int*)alloc(4096);
    float*    dis   = (float*)alloc((size_t)N * 4);
    int2*     edge  = (int2*)alloc((size_t)(E + 16) * 8);
    __half*   xh    = (__half*)alloc((size_t)N * 16 * 2);
    float*    p0    = (float*)alloc((size_t)N * 16 * 4);
    __half*   bufA  = (__half*)alloc((size_t)N * 64 * 2);
    __half*   bufB  = (__half*)alloc((size_t)N * 64 * 2);
    unsigned* gmax  = (unsigned*)alloc((size_t)G_GRAPHS * 64 * 4);

    hipMemsetAsync(deg, 0, (size_t)N * 4, stream);
    hipMemsetAsync(cnt, 0, (size_t)N * 4, stream);
    hipMemsetAsync(edge + E, 0, 16 * 8, stream);   // zero pad for clamped loads

    const int EB = (E + 255) / 256;
    const int NB = (N + 255) / 256;
    const int PB = 2048;   // persistent prop blocks

    k_count<<<EB, 256, 0, stream>>>(edst, deg, E);
    k_dis<<<NB, 256, 0, stream>>>(deg, dis, N);
    k_scanA<<<NB, 256, 0, stream>>>(deg, rowst, bsum, N);
    k_scanB<<<1, 512, 0, stream>>>(bsum, NB);
    k_scanC<<<NB, 256, 0, stream>>>(rowst, bsum, N);
    k_fill<<<EB, 256, 0, stream>>>(esrc, edst, dis, rowst, cnt, edge, E);
    k_x2h<<<(N * 4 + 255) / 256, 256, 0, stream>>>(x, xh, N * 4);

    // encoder: p0 = prop(x); y2 = relu(p0@W1+b1)@W2
    k_prop16<<<(N + 63) / 64, 256, 0, stream>>>(xh, p0, dis, rowst, deg, edge, N);
    k_dense<<<(N + 15) / 16, 256, 0, stream>>>(p0, bufA, W1, b1, W2, N);
    // z2 = prop(y2)+b2; out = z2@Wg1
    k_prop64<<<PB, 256, 0, stream>>>(bufA, bufB, dis, rowst, deg, edge, b2, 0, Wg1, nullptr, N);
    // z3 = relu(prop(.)+bg1); out = z3@Wg2
    k_prop64<<<PB, 256, 0, stream>>>(bufB, bufA, dis, rowst, deg, edge, bg1, 1, Wg2, nullptr, N);
    // z4 = relu(prop(.)+bg2); out = z4@Wg3
    k_prop64<<<PB, 256, 0, stream>>>(bufA, bufB, dis, rowst, deg, edge, bg2, 1, Wg3, nullptr, N);
    // z5 = relu(prop(.)+bg3)
    k_prop64<<<PB, 256, 0, stream>>>(bufB, bufA, dis, rowst, deg, edge, bg3, 1, nullptr, nullptr, N);
    // SGConv: 3 plain props, then prop + @Wsg + bsg
    k_prop64<<<PB, 256, 0, stream>>>(bufA, bufB, dis, rowst, deg, edge, nullptr, 0, nullptr, nullptr, N);
    k_prop64<<<PB, 256, 0, stream>>>(bufB, bufA, dis, rowst, deg, edge, nullptr, 0, nullptr, nullptr, N);
    k_prop64<<<PB, 256, 0, stream>>>(bufA, bufB, dis, rowst, deg, edge, nullptr, 0, nullptr, nullptr, N);
    k_prop64<<<PB, 256, 0, stream>>>(bufB, bufA, dis, rowst, deg, edge, nullptr, 0, Wsg, bsg, N);

    // pool + head
    k_pool_init<<<G_GRAPHS, 64, 0, stream>>>(gmax);
    k_pool<<<(N + 127) / 128, 256, 0, stream>>>(bufA, batch, gmax, N);
    k_head<<<1, 64, 0, stream>>>(gmax, Wf1, bf1, Wf2, bf2, Wc, bc, Wcb, bcb, (float*)d_out);
}